// Round 5
// baseline (301.094 us; speedup 1.0000x reference)
//
#include <hip/hip_runtime.h>

#define FEPS 1e-12f

typedef __attribute__((ext_vector_type(8))) short short8;   // 8 bf16 = 4 VGPR
typedef __attribute__((ext_vector_type(4))) float floatx4;  // MFMA C/D

constexpr int NB = 64, D = 256, T = 4096, K = 64, S = 8;
constexpr int TC = 32;            // pixels per chunk (per group)
constexpr int TBLK = T / S;       // 512 pixels per block
constexpr int NCHG = TBLK / TC / 2;  // 8 chunks per group

// f32 -> bf16 round-to-nearest-even
__device__ __forceinline__ unsigned short f2bf(float f) {
    unsigned u = __float_as_uint(f);
    return (unsigned short)((u + 0x7FFFu + ((u >> 16) & 1u)) >> 16);
}
__device__ __forceinline__ unsigned pk2(float a, float b) {
    return (unsigned)f2bf(a) | ((unsigned)f2bf(b) << 16);
}

// Workgroup barrier WITHOUT the implicit vmcnt(0) drain __syncthreads emits.
// lgkmcnt(0) orders our ds ops; register-destined global prefetch loads
// legally stay in flight across it.
__device__ __forceinline__ void barrier_nodrain() {
    __builtin_amdgcn_sched_barrier(0);
    asm volatile("s_waitcnt lgkmcnt(0)" ::: "memory");
    __builtin_amdgcn_s_barrier();
    __builtin_amdgcn_sched_barrier(0);
}

// Fused: L2-norm factor + logits MFMA-GEMM + softmax + aggregation MFMA-GEMM.
// 512 threads = 2 independent 4-wave GROUPS; group grp handles chunks 2i+grp
// with private LDS buffers. Both groups share the block-wide barrier cadence,
// so their global prefetches (adjacent 128B halves of 256B lines) issue in
// the same window -> L2 merges -> no fetch amplification (the R4 failure).
// LDS 2x37.5KB -> 2 blocks/CU = 16 waves/CU. grid=(S=8, NB) = 512 = 2/CU.
__global__ __launch_bounds__(512, 4)
void nv_main(const float* __restrict__ x, const float* __restrict__ w,
             float* __restrict__ vout, float* __restrict__ suma)
{
    __shared__ unsigned short xs1[2][TC * D];  // [t][d ^ 8t]  GEMM1 B (16 KB ea)
    __shared__ unsigned short xs2[2][D * TC];  // [d][t]       GEMM2 B (16 KB ea)
    __shared__ unsigned short bm[2][K * TC];   // [k][t]       GEMM2 A (4 KB ea)
    __shared__ float sps[2][TC][4];            // softmax denom partials
    __shared__ float sqp[2][4][TC];            // sumsq partials

    const int tid = threadIdx.x;
    const int grp = tid >> 8;                  // wave-group 0/1
    const int wv = (tid >> 6) & 3, ln = tid & 63;
    const int m = ln & 15, g = ln >> 4;        // MFMA lane decomposition
    const int dr = ln >> 3, q = ln & 7;        // staging decomposition
    const int n = blockIdx.y;

    const float* xn = x + (size_t)n * D * T;

    // Resident W A-frags: wave wv owns GEMM1 k-band [16wv, 16wv+16)
    short8 wf[8];
    {
        const float* wp = w + (16 * wv + m) * D + 8 * g;
        #pragma unroll
        for (int ks = 0; ks < 8; ++ks) {
            float4 q0 = *(const float4*)(wp + 32 * ks);
            float4 q1 = *(const float4*)(wp + 32 * ks + 4);
            union { short8 v; unsigned u[4]; } t_;
            t_.u[0] = pk2(q0.x, q0.y); t_.u[1] = pk2(q0.z, q0.w);
            t_.u[2] = pk2(q1.x, q1.y); t_.u[3] = pk2(q1.z, q1.w);
            wf[ks] = t_.v;
        }
    }

    floatx4 acc[4][4];                       // GEMM2 acc [mt(k)][nt2(d)]
    floatx4 fzero = {0.f, 0.f, 0.f, 0.f};
    #pragma unroll
    for (int a = 0; a < 4; ++a)
        #pragma unroll
        for (int b = 0; b < 4; ++b) acc[a][b] = fzero;
    float sa[4] = {0.f, 0.f, 0.f, 0.f};      // sum_t a for k = 16wv+4g+reg

    // ---- prologue: prefetch this group's chunk 0 (8 float4/thread)
    float4 pv[8];
    {
        const int t0 = blockIdx.x * TBLK + grp * TC;
        #pragma unroll
        for (int s = 0; s < 8; ++s)
            pv[s] = *(const float4*)(xn + (size_t)(64 * wv + 8 * s + dr) * T
                                     + t0 + 4 * q);
    }

    for (int i = 0; i < NCHG; ++i) {
        barrier_nodrain();                   // xs/bm free (prev chunk done)

        // ---- stage: pv (f32) -> bf16 into xs2 [d][t] and xs1 [t][d] (4x4
        //      lane transpose across dr&3 via shfl_xor 8/16), sumsq fused
        float4 sq4 = {0.f, 0.f, 0.f, 0.f};
        #pragma unroll
        for (int s = 0; s < 8; ++s) {
            const int d = 64 * wv + 8 * s + dr;
            float4 v = pv[s];
            sq4.x = fmaf(v.x, v.x, sq4.x); sq4.y = fmaf(v.y, v.y, sq4.y);
            sq4.z = fmaf(v.z, v.z, sq4.z); sq4.w = fmaf(v.w, v.w, sq4.w);
            unsigned lo = pk2(v.x, v.y), hi = pk2(v.z, v.w);
            uint2 st2; st2.x = lo; st2.y = hi;          // 4 bf16 along t
            *(uint2*)(&xs2[grp][d * TC + 4 * q]) = st2;
            // 4x4 bf16 transpose across lanes dr&3 (d rows <-> t cols)
            unsigned plo = __shfl_xor(lo, 8), phi = __shfl_xor(hi, 8);
            unsigned lo1, hi1;
            if ((dr & 1) == 0) { lo1 = (lo & 0xFFFFu) | (plo << 16);
                                 hi1 = (hi & 0xFFFFu) | (phi << 16); }
            else               { lo1 = (lo >> 16) | (plo & 0xFFFF0000u);
                                 hi1 = (hi >> 16) | (phi & 0xFFFF0000u); }
            unsigned slo = __shfl_xor(lo1, 16), shi = __shfl_xor(hi1, 16);
            uint2 ot;
            if ((dr & 2) == 0) { ot.x = lo1; ot.y = slo; }
            else               { ot.x = shi; ot.y = hi1; }
            const int tt = 4 * q + (dr & 3);            // t this lane owns
            const int db = 64 * wv + 8 * s + 4 * (dr >> 2);
            *(uint2*)(&xs1[grp][tt * D + (db ^ (8 * tt))]) = ot;
        }
        // per-t sumsq partial (this wave's 64 d's): reduce over dr
        #pragma unroll
        for (int msk = 8; msk <= 32; msk <<= 1) {
            sq4.x += __shfl_xor(sq4.x, msk); sq4.y += __shfl_xor(sq4.y, msk);
            sq4.z += __shfl_xor(sq4.z, msk); sq4.w += __shfl_xor(sq4.w, msk);
        }
        if (ln < 8) *(float4*)(&sqp[grp][wv][4 * ln]) = sq4;
        barrier_nodrain();                   // publish xs1/xs2/sqp

        // ---- prefetch next chunk (stays in flight across all phases);
        //      both groups issue in this same window -> 256B line merge
        if (i + 1 < NCHG) {
            const int tn = blockIdx.x * TBLK + (2 * (i + 1) + grp) * TC;
            #pragma unroll
            for (int s = 0; s < 8; ++s)
                pv[s] = *(const float4*)(xn + (size_t)(64 * wv + 8 * s + dr) * T
                                         + tn + 4 * q);
        }

        // ---- r[t] = 1/max(||x[:,t]||,eps) for this lane's 2 t-columns
        float r4[2];
        #pragma unroll
        for (int nt = 0; nt < 2; ++nt) {
            const int t = 16 * nt + m;
            float ss = sqp[grp][0][t] + sqp[grp][1][t]
                     + sqp[grp][2][t] + sqp[grp][3][t];
            r4[nt] = 1.f / fmaxf(sqrtf(ss), FEPS);
        }

        // ---- GEMM1: z[16 k][32 t] = W * x  (contract d=256)
        floatx4 z[2];
        z[0] = fzero; z[1] = fzero;
        #pragma unroll
        for (int ks = 0; ks < 8; ++ks) {
            #pragma unroll
            for (int nt = 0; nt < 2; ++nt) {
                const int t = 16 * nt + m;
                short8 bfr = *(const short8*)(
                    &xs1[grp][t * D + ((32 * ks + 8 * g) ^ (8 * t))]);
                z[nt] = __builtin_amdgcn_mfma_f32_16x16x32_bf16(
                    wf[ks], bfr, z[nt], 0, 0, 0);
            }
        }

        // ---- softmax over k (no max-sub: |logit| <= ||w_row|| ~ 1)
        float e[2][4], psum[2];
        #pragma unroll
        for (int nt = 0; nt < 2; ++nt) {
            const float r = r4[nt];
            float p = 0.f;
            #pragma unroll
            for (int reg = 0; reg < 4; ++reg) {
                float ex = __expf(z[nt][reg] * r);
                e[nt][reg] = ex; p += ex;
            }
            psum[nt] = p;
        }
        #pragma unroll
        for (int nt = 0; nt < 2; ++nt) {     // reduce over g: wave's 16 k's
            psum[nt] += __shfl_xor(psum[nt], 16);
            psum[nt] += __shfl_xor(psum[nt], 32);
        }
        if (g == 0) {
            #pragma unroll
            for (int nt = 0; nt < 2; ++nt) sps[grp][16 * nt + m][wv] = psum[nt];
        }
        barrier_nodrain();                   // publish sps
        #pragma unroll
        for (int nt = 0; nt < 2; ++nt) {
            const int t = 16 * nt + m;
            float4 sv = *(const float4*)(&sps[grp][t][0]);
            const float inv = 1.f / (sv.x + sv.y + sv.z + sv.w);
            const float br = inv * r4[nt];
            #pragma unroll
            for (int reg = 0; reg < 4; ++reg) {
                const int k = 16 * wv + 4 * g + reg;
                bm[grp][k * TC + t] = f2bf(e[nt][reg] * br);
                sa[reg] += e[nt][reg] * inv;
            }
        }
        barrier_nodrain();                   // publish bm

        // ---- GEMM2: acc[k][d] += b[k][t] * x[d][t]  (contract t=32)
        {
            short8 af[4], bf[4];
            #pragma unroll
            for (int mt = 0; mt < 4; ++mt)
                af[mt] = *(const short8*)(&bm[grp][(16 * mt + m) * TC + 8 * g]);
            #pragma unroll
            for (int nt2 = 0; nt2 < 4; ++nt2)
                bf[nt2] = *(const short8*)(
                    &xs2[grp][(64 * wv + 16 * nt2 + m) * TC + 8 * g]);
            #pragma unroll
            for (int mt = 0; mt < 4; ++mt)
                #pragma unroll
                for (int nt2 = 0; nt2 < 4; ++nt2)
                    acc[mt][nt2] = __builtin_amdgcn_mfma_f32_16x16x32_bf16(
                        af[mt], bf[nt2], acc[mt][nt2], 0, 0, 0);
        }
    }

    // ---- flush vlad partials (8 t-split blocks per n, f32 atomics) + suma
    float* vs = vout + (size_t)n * K * D;
    #pragma unroll
    for (int mt = 0; mt < 4; ++mt)
        #pragma unroll
        for (int nt2 = 0; nt2 < 4; ++nt2)
            #pragma unroll
            for (int reg = 0; reg < 4; ++reg)
                atomicAdd(&vs[(16 * mt + 4 * g + reg) * D
                              + 64 * wv + 16 * nt2 + m], acc[mt][nt2][reg]);
    #pragma unroll
    for (int reg = 0; reg < 4; ++reg) {
        float v = sa[reg];
        v += __shfl_xor(v, 1); v += __shfl_xor(v, 2);
        v += __shfl_xor(v, 4); v += __shfl_xor(v, 8);
        if (m == 0) atomicAdd(&suma[n * K + 16 * wv + 4 * g + reg], v);
    }
}

// per (n,k): subtract suma*centroid, intra-normalize over d, accum final sumsq
__global__ void nv_finish_row(const float* __restrict__ cent,
                              const float* __restrict__ suma,
                              float* __restrict__ out,
                              float* __restrict__ nsum)
{
    const int bid = blockIdx.x;          // n*64 + k
    const int nn = bid >> 6, k = bid & 63;
    const int d = threadIdx.x;
    float v = out[(size_t)bid * D + d] - suma[bid] * cent[k * D + d];
    float sv = v * v;
    #pragma unroll
    for (int msk = 1; msk < 64; msk <<= 1) sv += __shfl_xor(sv, msk);
    __shared__ float red[4];
    __shared__ float stot;
    if ((d & 63) == 0) red[d >> 6] = sv;
    __syncthreads();
    if (d == 0) stot = red[0] + red[1] + red[2] + red[3];
    __syncthreads();
    const float s = stot;
    const float inv = 1.f / fmaxf(sqrtf(s), FEPS);
    out[(size_t)bid * D + d] = v * inv;
    if (d == 0) atomicAdd(&nsum[nn], s * inv * inv);
}

// final L2 over the flattened (K*D) per n
__global__ void nv_final(float* __restrict__ out, const float* __restrict__ nsum) {
    const int idx = blockIdx.x * 256 + threadIdx.x;
    const int n = idx >> 14;             // /16384
    out[idx] *= 1.f / fmaxf(sqrtf(nsum[n]), FEPS);
}

extern "C" void kernel_launch(void* const* d_in, const int* in_sizes, int n_in,
                              void* d_out, int out_size, void* d_ws, size_t ws_size,
                              hipStream_t stream)
{
    const float* x    = (const float*)d_in[0];
    const float* w    = (const float*)d_in[1];
    const float* cent = (const float*)d_in[2];
    float* out = (float*)d_out;

    // ws layout: suma[NB*K] | nsum[NB]
    float* suma = (float*)d_ws;
    float* nsum = suma + NB * K;

    hipMemsetAsync(d_ws, 0, (size_t)(NB * K + NB) * sizeof(float), stream);
    hipMemsetAsync(d_out, 0, (size_t)NB * K * D * sizeof(float), stream);

    dim3 g(S, NB);
    nv_main<<<g, 512, 0, stream>>>(x, w, out, suma);
    nv_finish_row<<<NB * K, 256, 0, stream>>>(cent, suma, out, nsum);
    nv_final<<<(NB * K * D) / 256, 256, 0, stream>>>(out, nsum);
}

// Round 6
// 233.997 us; speedup vs baseline: 1.2867x; 1.2867x over previous
//
#include <hip/hip_runtime.h>

#define FEPS 1e-12f

typedef __attribute__((ext_vector_type(8))) short short8;   // 8 bf16 = 4 VGPR
typedef __attribute__((ext_vector_type(4))) float floatx4;  // MFMA C/D

constexpr int NB = 64, D = 256, T = 4096, K = 64, S = 8;
constexpr int TC = 64;           // pixels per chunk
constexpr int TBLK = T / S;      // 512 pixels per block
constexpr int NCH = TBLK / TC;   // 8 chunks

// f32 -> bf16 round-to-nearest-even
__device__ __forceinline__ unsigned short f2bf(float f) {
    unsigned u = __float_as_uint(f);
    return (unsigned short)((u + 0x7FFFu + ((u >> 16) & 1u)) >> 16);
}
__device__ __forceinline__ unsigned pk2(float a, float b) {
    return (unsigned)f2bf(a) | ((unsigned)f2bf(b) << 16);
}

// Workgroup barrier WITHOUT the implicit vmcnt(0) drain __syncthreads emits.
// lgkmcnt(0) orders our ds ops; register-destined global prefetch loads
// legally stay in flight across it.
__device__ __forceinline__ void barrier_nodrain() {
    __builtin_amdgcn_sched_barrier(0);
    asm volatile("s_waitcnt lgkmcnt(0)" ::: "memory");
    __builtin_amdgcn_s_barrier();
    __builtin_amdgcn_s_barrier();  // (no-op dedup safety; single barrier kept below)
}

// NOTE: single-barrier version (the above double call would be wasteful)
__device__ __forceinline__ void barrier_nd() {
    __builtin_amdgcn_sched_barrier(0);
    asm volatile("s_waitcnt lgkmcnt(0)" ::: "memory");
    __builtin_amdgcn_s_barrier();
    __builtin_amdgcn_sched_barrier(0);
}

// Fused: L2-norm factor + logits MFMA-GEMM + softmax + aggregation MFMA-GEMM.
// One 512-thread (8-wave) block per (t-split, n); TC=64 so EVERY global load
// instruction covers 4 rows x 256B contiguous (clean HBM bursts - the R4/R5
// fetch amplification was 128B-footprint instructions). LDS 75KB -> 2
// blocks/CU = 16 waves/CU. Epilogue flushes via LDS reassembly so atomicAdd
// bursts are 64 lanes x 4B = 256B contiguous (no write amplification).
__global__ __launch_bounds__(512, 4)
void nv_main(const float* __restrict__ x, const float* __restrict__ w,
             float* __restrict__ vout, float* __restrict__ suma)
{
    __shared__ __align__(16) unsigned char smem[76800];
    unsigned short* xs1 = (unsigned short*)smem;            // [t][d^swz] 32KB
    unsigned short* xs2 = (unsigned short*)(smem + 32768);  // [d][t^swz] 32KB
    unsigned short* bmm = (unsigned short*)(smem + 65536);  // [k][t^swz]  8KB
    float* sps = (float*)(smem + 73728);                    // [t][4] denom
    float* sqp = (float*)(smem + 74752);                    // [wv][64] sumsq
    float* fb  = (float*)smem;                              // epilogue [k][d]

    const int tid = threadIdx.x;
    const int wv = tid >> 6, ln = tid & 63;
    const int m = ln & 15, g = ln >> 4;     // MFMA/staging lane decomposition
    const int a = wv & 3, b = wv >> 2;      // GEMM1: k-band a, t-half b
    const int n = blockIdx.y;

    const float* xn = x + (size_t)n * D * T;

    // Resident W A-frags for k-band a = [16a, 16a+16)
    short8 wf[8];
    {
        const float* wp = w + (16 * a + m) * D + 8 * g;
        #pragma unroll
        for (int ks = 0; ks < 8; ++ks) {
            float4 q0 = *(const float4*)(wp + 32 * ks);
            float4 q1 = *(const float4*)(wp + 32 * ks + 4);
            union { short8 v; unsigned u[4]; } t_;
            t_.u[0] = pk2(q0.x, q0.y); t_.u[1] = pk2(q0.z, q0.w);
            t_.u[2] = pk2(q1.x, q1.y); t_.u[3] = pk2(q1.z, q1.w);
            wf[ks] = t_.v;
        }
    }

    floatx4 acc[4][2];                       // GEMM2 acc [mt(k)][nt2(d)]
    floatx4 fzero = {0.f, 0.f, 0.f, 0.f};
    #pragma unroll
    for (int p = 0; p < 4; ++p) { acc[p][0] = fzero; acc[p][1] = fzero; }
    float sa[4] = {0.f, 0.f, 0.f, 0.f};      // sum_t a for k = 16a+4g+reg

    // ---- prologue: prefetch chunk 0 (8 float4/thread; 4 rows x 256B / instr)
    float4 pv[8];
    {
        const int t0 = blockIdx.x * TBLK;
        #pragma unroll
        for (int s = 0; s < 8; ++s)
            pv[s] = *(const float4*)(xn + (size_t)(32 * wv + 4 * s + g) * T
                                     + t0 + 4 * m);
    }

    for (int c = 0; c < NCH; ++c) {
        barrier_nd();                        // xs/bm free (prev chunk done)

        // ---- stage: pv (f32) -> bf16 into xs2 [d][t] and xs1 [t][d] (4x4
        //      lane transpose across g via shfl_xor 16/32), sumsq fused
        float4 sq4 = {0.f, 0.f, 0.f, 0.f};
        #pragma unroll
        for (int s = 0; s < 8; ++s) {
            const int d = 32 * wv + 4 * s + g;
            float4 v = pv[s];
            sq4.x = fmaf(v.x, v.x, sq4.x); sq4.y = fmaf(v.y, v.y, sq4.y);
            sq4.z = fmaf(v.z, v.z, sq4.z); sq4.w = fmaf(v.w, v.w, sq4.w);
            unsigned lo = pk2(v.x, v.y), hi = pk2(v.z, v.w);
            uint2 st2; st2.x = lo; st2.y = hi;          // 4 bf16 along t
            *(uint2*)(&xs2[d * TC + ((4 * m) ^ (8 * (d & 7)))]) = st2;
            // 4x4 bf16 transpose across lanes g (d rows <-> t cols)
            unsigned plo = __shfl_xor(lo, 16), phi = __shfl_xor(hi, 16);
            unsigned lo1, hi1;
            if ((g & 1) == 0) { lo1 = (lo & 0xFFFFu) | (plo << 16);
                                hi1 = (hi & 0xFFFFu) | (phi << 16); }
            else              { lo1 = (lo >> 16) | (plo & 0xFFFF0000u);
                                hi1 = (hi >> 16) | (phi & 0xFFFF0000u); }
            unsigned slo = __shfl_xor(lo1, 32), shi = __shfl_xor(hi1, 32);
            uint2 ot;
            if ((g & 2) == 0) { ot.x = lo1; ot.y = slo; }
            else              { ot.x = shi; ot.y = hi1; }
            const int tt = 4 * m + g;                   // t this lane owns
            const int db = 32 * wv + 4 * s;             // 4 d's, ascending
            *(uint2*)(&xs1[tt * D + (db ^ (8 * (tt & 31)))]) = ot;
        }
        // per-t sumsq partial (this wave's 32 d's): reduce over g
        #pragma unroll
        for (int msk = 16; msk <= 32; msk <<= 1) {
            sq4.x += __shfl_xor(sq4.x, msk); sq4.y += __shfl_xor(sq4.y, msk);
            sq4.z += __shfl_xor(sq4.z, msk); sq4.w += __shfl_xor(sq4.w, msk);
        }
        if (g == 0) *(float4*)(&sqp[wv * 64 + 4 * m]) = sq4;
        barrier_nd();                        // publish xs1/xs2/sqp

        // ---- prefetch chunk c+1 (stays in flight across all phases)
        if (c + 1 < NCH) {
            const int tn = blockIdx.x * TBLK + (c + 1) * TC;
            #pragma unroll
            for (int s = 0; s < 8; ++s)
                pv[s] = *(const float4*)(xn + (size_t)(32 * wv + 4 * s + g) * T
                                         + tn + 4 * m);
        }

        // ---- r[t] = 1/max(||x[:,t]||,eps) for this wave's 2 t-columns
        float r4[2];
        #pragma unroll
        for (int nt = 0; nt < 2; ++nt) {
            const int t = 32 * b + 16 * nt + m;
            float ss = 0.f;
            #pragma unroll
            for (int j = 0; j < 8; ++j) ss += sqp[j * 64 + t];
            r4[nt] = 1.f / fmaxf(sqrtf(ss), FEPS);
        }

        // ---- GEMM1: z[16 k][32 t] = W * x  (contract d=256)
        floatx4 z[2];
        z[0] = fzero; z[1] = fzero;
        #pragma unroll
        for (int ks = 0; ks < 8; ++ks) {
            #pragma unroll
            for (int nt = 0; nt < 2; ++nt) {
                const int t = 32 * b + 16 * nt + m;
                short8 bfr = *(const short8*)(
                    &xs1[t * D + ((32 * ks + 8 * g) ^ (8 * (t & 31)))]);
                z[nt] = __builtin_amdgcn_mfma_f32_16x16x32_bf16(
                    wf[ks], bfr, z[nt], 0, 0, 0);
            }
        }

        // ---- softmax over k (no max-sub: |logit| <= ||w_row|| ~ 1)
        float e[2][4], psum[2];
        #pragma unroll
        for (int nt = 0; nt < 2; ++nt) {
            const float r = r4[nt];
            float p = 0.f;
            #pragma unroll
            for (int reg = 0; reg < 4; ++reg) {
                float ex = __expf(z[nt][reg] * r);
                e[nt][reg] = ex; p += ex;
            }
            psum[nt] = p;
        }
        #pragma unroll
        for (int nt = 0; nt < 2; ++nt) {     // reduce over g: wave's 16 k's
            psum[nt] += __shfl_xor(psum[nt], 16);
            psum[nt] += __shfl_xor(psum[nt], 32);
        }
        if (g == 0) {
            #pragma unroll
            for (int nt = 0; nt < 2; ++nt)
                sps[(32 * b + 16 * nt + m) * 4 + a] = psum[nt];
        }
        barrier_nd();                        // publish sps
        #pragma unroll
        for (int nt = 0; nt < 2; ++nt) {
            const int t = 32 * b + 16 * nt + m;
            float4 sv = *(const float4*)(&sps[t * 4]);
            const float inv = 1.f / (sv.x + sv.y + sv.z + sv.w);
            const float br = inv * r4[nt];
            #pragma unroll
            for (int reg = 0; reg < 4; ++reg) {
                const int k = 16 * a + 4 * g + reg;
                bmm[k * TC + (t ^ (8 * (k & 7)))] = f2bf(e[nt][reg] * br);
                sa[reg] += e[nt][reg] * inv;
            }
        }
        barrier_nd();                        // publish bm

        // ---- GEMM2: acc[k][d] += b[k][t] * x[d][t]  (contract t=64)
        #pragma unroll
        for (int kt = 0; kt < 2; ++kt) {
            short8 af[4], bf[2];
            #pragma unroll
            for (int mt = 0; mt < 4; ++mt) {
                const int k = 16 * mt + m;
                af[mt] = *(const short8*)(
                    &bmm[k * TC + ((32 * kt + 8 * g) ^ (8 * (k & 7)))]);
            }
            #pragma unroll
            for (int nt2 = 0; nt2 < 2; ++nt2) {
                const int d = 32 * wv + 16 * nt2 + m;
                bf[nt2] = *(const short8*)(
                    &xs2[d * TC + ((32 * kt + 8 * g) ^ (8 * (d & 7)))]);
            }
            #pragma unroll
            for (int mt = 0; mt < 4; ++mt)
                #pragma unroll
                for (int nt2 = 0; nt2 < 2; ++nt2)
                    acc[mt][nt2] = __builtin_amdgcn_mfma_f32_16x16x32_bf16(
                        af[mt], bf[nt2], acc[mt][nt2], 0, 0, 0);
        }
    }

    // ---- epilogue: reassemble block partial in LDS, flush with 256B bursts
    barrier_nd();                            // xs dead -> reuse as fb [k][d]
    #pragma unroll
    for (int mt = 0; mt < 4; ++mt)
        #pragma unroll
        for (int nt2 = 0; nt2 < 2; ++nt2)
            #pragma unroll
            for (int reg = 0; reg < 4; ++reg)
                fb[(16 * mt + 4 * g + reg) * D + 32 * wv + 16 * nt2 + m] =
                    acc[mt][nt2][reg];
    barrier_nd();
    {
        float* vs = vout + (size_t)n * K * D;
        #pragma unroll
        for (int j = 0; j < 32; ++j) {
            const int off = wv * 2048 + j * 64 + ln;  // 64 lanes x 4B = 256B
            atomicAdd(&vs[off], fb[off]);
        }
    }
    #pragma unroll
    for (int reg = 0; reg < 4; ++reg) {
        float v = sa[reg];
        v += __shfl_xor(v, 1); v += __shfl_xor(v, 2);
        v += __shfl_xor(v, 4); v += __shfl_xor(v, 8);
        if (m == 0) atomicAdd(&suma[n * K + 16 * a + 4 * g + reg], v);
    }
}

// per (n,k): subtract suma*centroid, intra-normalize over d, accum final sumsq
__global__ void nv_finish_row(const float* __restrict__ cent,
                              const float* __restrict__ suma,
                              float* __restrict__ out,
                              float* __restrict__ nsum)
{
    const int bid = blockIdx.x;          // n*64 + k
    const int nn = bid >> 6, k = bid & 63;
    const int d = threadIdx.x;
    float v = out[(size_t)bid * D + d] - suma[bid] * cent[k * D + d];
    float sv = v * v;
    #pragma unroll
    for (int msk = 1; msk < 64; msk <<= 1) sv += __shfl_xor(sv, msk);
    __shared__ float red[4];
    __shared__ float stot;
    if ((d & 63) == 0) red[d >> 6] = sv;
    __syncthreads();
    if (d == 0) stot = red[0] + red[1] + red[2] + red[3];
    __syncthreads();
    const float s = stot;
    const float inv = 1.f / fmaxf(sqrtf(s), FEPS);
    out[(size_t)bid * D + d] = v * inv;
    if (d == 0) atomicAdd(&nsum[nn], s * inv * inv);
}

// final L2 over the flattened (K*D) per n
__global__ void nv_final(float* __restrict__ out, const float* __restrict__ nsum) {
    const int idx = blockIdx.x * 256 + threadIdx.x;
    const int n = idx >> 14;             // /16384
    out[idx] *= 1.f / fmaxf(sqrtf(nsum[n]), FEPS);
}

extern "C" void kernel_launch(void* const* d_in, const int* in_sizes, int n_in,
                              void* d_out, int out_size, void* d_ws, size_t ws_size,
                              hipStream_t stream)
{
    const float* x    = (const float*)d_in[0];
    const float* w    = (const float*)d_in[1];
    const float* cent = (const float*)d_in[2];
    float* out = (float*)d_out;

    // ws layout: suma[NB*K] | nsum[NB]
    float* suma = (float*)d_ws;
    float* nsum = suma + NB * K;

    hipMemsetAsync(d_ws, 0, (size_t)(NB * K + NB) * sizeof(float), stream);
    hipMemsetAsync(d_out, 0, (size_t)NB * K * D * sizeof(float), stream);

    dim3 g(S, NB);
    nv_main<<<g, 512, 0, stream>>>(x, w, out, suma);
    nv_finish_row<<<NB * K, 256, 0, stream>>>(cent, suma, out, nsum);
    nv_final<<<(NB * K * D) / 256, 256, 0, stream>>>(out, nsum);
}

// Round 7
// 140.746 us; speedup vs baseline: 2.1393x; 1.6625x over previous
//
#include <hip/hip_runtime.h>

#define FEPS 1e-12f

typedef __attribute__((ext_vector_type(8))) short short8;   // 8 bf16 = 4 VGPR
typedef __attribute__((ext_vector_type(4))) float floatx4;  // MFMA C/D

constexpr int NB = 64, D = 256, T = 4096, K = 64, S = 8;
constexpr int TC = 64;           // pixels per chunk
constexpr int TBLK = T / S;      // 512 pixels per block
constexpr int NCH = TBLK / TC;   // 8 chunks

// f32 -> bf16 round-to-nearest-even
__device__ __forceinline__ unsigned short f2bf(float f) {
    unsigned u = __float_as_uint(f);
    return (unsigned short)((u + 0x7FFFu + ((u >> 16) & 1u)) >> 16);
}
__device__ __forceinline__ unsigned pk2(float a, float b) {
    return (unsigned)f2bf(a) | ((unsigned)f2bf(b) << 16);
}

// Workgroup barrier WITHOUT the implicit vmcnt(0) drain __syncthreads emits.
// lgkmcnt(0) orders our ds ops; register-destined global prefetch loads
// legally stay in flight across it.
__device__ __forceinline__ void barrier_nd() {
    __builtin_amdgcn_sched_barrier(0);
    asm volatile("s_waitcnt lgkmcnt(0)" ::: "memory");
    __builtin_amdgcn_s_barrier();
    __builtin_amdgcn_sched_barrier(0);
}

// Fused: L2-norm factor + logits MFMA-GEMM + softmax + aggregation MFMA-GEMM.
// One 512-thread (8-wave) block per (n, t-split). TC=64: every global load
// instruction covers 4 rows x 256B contiguous (clean HBM bursts). LDS 75KB ->
// 2 blocks/CU = 16 waves/CU. __launch_bounds__(512,2): 2 blocks/CU -> 128
// VGPR cap (the R6 (512,4) bound capped at 64 and spilled to scratch).
// Grid is FLAT 512; bid%8 selects both the XCD (round-robin dispatch) and the
// n-octet, so all 8 t-split blocks of one n share an XCD -> vlad atomic lines
// stay in one L2 (no cross-XCD ping-pong).
__global__ __launch_bounds__(512, 2)
void nv_main(const float* __restrict__ x, const float* __restrict__ w,
             float* __restrict__ vout, float* __restrict__ suma)
{
    __shared__ __align__(16) unsigned char smem[76800];
    unsigned short* xs1 = (unsigned short*)smem;            // [t][d^swz] 32KB
    unsigned short* xs2 = (unsigned short*)(smem + 32768);  // [d][t^swz] 32KB
    unsigned short* bmm = (unsigned short*)(smem + 65536);  // [k][t^swz]  8KB
    float* sps = (float*)(smem + 73728);                    // [t][4] denom
    float* sqp = (float*)(smem + 74752);                    // [wv][64] sumsq
    float* fb  = (float*)smem;                              // epilogue [k][d]

    const int tid = threadIdx.x;
    const int wv = tid >> 6, ln = tid & 63;
    const int m = ln & 15, g = ln >> 4;     // MFMA/staging lane decomposition
    const int a = wv & 3, b = wv >> 2;      // GEMM1: k-band a, t-half b
    const int bid = blockIdx.x;
    const int n = (bid & 7) * 8 + ((bid >> 3) & 7);   // XCD-confined n octet
    const int ts = bid >> 6;                           // t-split 0..7

    const float* xn = x + (size_t)n * D * T;

    // Resident W A-frags for k-band a = [16a, 16a+16)
    short8 wf[8];
    {
        const float* wp = w + (16 * a + m) * D + 8 * g;
        #pragma unroll
        for (int ks = 0; ks < 8; ++ks) {
            float4 q0 = *(const float4*)(wp + 32 * ks);
            float4 q1 = *(const float4*)(wp + 32 * ks + 4);
            union { short8 v; unsigned u[4]; } t_;
            t_.u[0] = pk2(q0.x, q0.y); t_.u[1] = pk2(q0.z, q0.w);
            t_.u[2] = pk2(q1.x, q1.y); t_.u[3] = pk2(q1.z, q1.w);
            wf[ks] = t_.v;
        }
    }

    floatx4 acc[4][2];                       // GEMM2 acc [mt(k)][nt2(d)]
    floatx4 fzero = {0.f, 0.f, 0.f, 0.f};
    #pragma unroll
    for (int p = 0; p < 4; ++p) { acc[p][0] = fzero; acc[p][1] = fzero; }
    float sa[4] = {0.f, 0.f, 0.f, 0.f};      // sum_t a for k = 16a+4g+reg

    // ---- prologue: prefetch chunk 0 (8 float4/thread; 4 rows x 256B / instr)
    float4 pv[8];
    {
        const int t0 = ts * TBLK;
        #pragma unroll
        for (int s = 0; s < 8; ++s)
            pv[s] = *(const float4*)(xn + (size_t)(32 * wv + 4 * s + g) * T
                                     + t0 + 4 * m);
    }

    for (int c = 0; c < NCH; ++c) {
        barrier_nd();                        // xs/bm free (prev chunk done)

        // ---- stage: pv (f32) -> bf16 into xs2 [d][t] and xs1 [t][d] (4x4
        //      lane transpose across g via shfl_xor 16/32), sumsq fused
        float4 sq4 = {0.f, 0.f, 0.f, 0.f};
        #pragma unroll
        for (int s = 0; s < 8; ++s) {
            const int d = 32 * wv + 4 * s + g;
            float4 v = pv[s];
            sq4.x = fmaf(v.x, v.x, sq4.x); sq4.y = fmaf(v.y, v.y, sq4.y);
            sq4.z = fmaf(v.z, v.z, sq4.z); sq4.w = fmaf(v.w, v.w, sq4.w);
            unsigned lo = pk2(v.x, v.y), hi = pk2(v.z, v.w);
            uint2 st2; st2.x = lo; st2.y = hi;          // 4 bf16 along t
            *(uint2*)(&xs2[d * TC + ((4 * m) ^ (8 * (d & 7)))]) = st2;
            // 4x4 bf16 transpose across lanes g (d rows <-> t cols)
            unsigned plo = __shfl_xor(lo, 16), phi = __shfl_xor(hi, 16);
            unsigned lo1, hi1;
            if ((g & 1) == 0) { lo1 = (lo & 0xFFFFu) | (plo << 16);
                                hi1 = (hi & 0xFFFFu) | (phi << 16); }
            else              { lo1 = (lo >> 16) | (plo & 0xFFFF0000u);
                                hi1 = (hi >> 16) | (phi & 0xFFFF0000u); }
            unsigned slo = __shfl_xor(lo1, 32), shi = __shfl_xor(hi1, 32);
            uint2 ot;
            if ((g & 2) == 0) { ot.x = lo1; ot.y = slo; }
            else              { ot.x = shi; ot.y = hi1; }
            const int tt = 4 * m + g;                   // t this lane owns
            const int db = 32 * wv + 4 * s;             // 4 d's, ascending
            *(uint2*)(&xs1[tt * D + (db ^ (8 * (tt & 31)))]) = ot;
        }

        // ---- prefetch chunk c+1 NOW (pv regs free; in flight across the
        //      barrier and all compute phases below)
        if (c + 1 < NCH) {
            const int tn = ts * TBLK + (c + 1) * TC;
            #pragma unroll
            for (int s = 0; s < 8; ++s)
                pv[s] = *(const float4*)(xn + (size_t)(32 * wv + 4 * s + g) * T
                                         + tn + 4 * m);
        }

        // per-t sumsq partial (this wave's 32 d's): reduce over g
        #pragma unroll
        for (int msk = 16; msk <= 32; msk <<= 1) {
            sq4.x += __shfl_xor(sq4.x, msk); sq4.y += __shfl_xor(sq4.y, msk);
            sq4.z += __shfl_xor(sq4.z, msk); sq4.w += __shfl_xor(sq4.w, msk);
        }
        if (g == 0) *(float4*)(&sqp[wv * 64 + 4 * m]) = sq4;
        barrier_nd();                        // publish xs1/xs2/sqp

        // ---- r[t] = 1/max(||x[:,t]||,eps) for this wave's 2 t-columns
        float r4[2];
        #pragma unroll
        for (int nt = 0; nt < 2; ++nt) {
            const int t = 32 * b + 16 * nt + m;
            float ss = 0.f;
            #pragma unroll
            for (int j = 0; j < 8; ++j) ss += sqp[j * 64 + t];
            r4[nt] = 1.f / fmaxf(sqrtf(ss), FEPS);
        }

        // ---- GEMM1: z[16 k][32 t] = W * x  (contract d=256)
        floatx4 z[2];
        z[0] = fzero; z[1] = fzero;
        #pragma unroll
        for (int ks = 0; ks < 8; ++ks) {
            #pragma unroll
            for (int nt = 0; nt < 2; ++nt) {
                const int t = 32 * b + 16 * nt + m;
                short8 bfr = *(const short8*)(
                    &xs1[t * D + ((32 * ks + 8 * g) ^ (8 * (t & 31)))]);
                z[nt] = __builtin_amdgcn_mfma_f32_16x16x32_bf16(
                    wf[ks], bfr, z[nt], 0, 0, 0);
            }
        }

        // ---- softmax over k (no max-sub: |logit| <= ||w_row|| ~ 1)
        float e[2][4], psum[2];
        #pragma unroll
        for (int nt = 0; nt < 2; ++nt) {
            const float r = r4[nt];
            float p = 0.f;
            #pragma unroll
            for (int reg = 0; reg < 4; ++reg) {
                float ex = __expf(z[nt][reg] * r);
                e[nt][reg] = ex; p += ex;
            }
            psum[nt] = p;
        }
        #pragma unroll
        for (int nt = 0; nt < 2; ++nt) {     // reduce over g: wave's 16 k's
            psum[nt] += __shfl_xor(psum[nt], 16);
            psum[nt] += __shfl_xor(psum[nt], 32);
        }
        if (g == 0) {
            #pragma unroll
            for (int nt = 0; nt < 2; ++nt)
                sps[(32 * b + 16 * nt + m) * 4 + a] = psum[nt];
        }
        barrier_nd();                        // publish sps
        #pragma unroll
        for (int nt = 0; nt < 2; ++nt) {
            const int t = 32 * b + 16 * nt + m;
            float4 sv = *(const float4*)(&sps[t * 4]);
            const float inv = 1.f / (sv.x + sv.y + sv.z + sv.w);
            const float br = inv * r4[nt];
            #pragma unroll
            for (int reg = 0; reg < 4; ++reg) {
                const int k = 16 * a + 4 * g + reg;
                bmm[k * TC + (t ^ (8 * (k & 7)))] = f2bf(e[nt][reg] * br);
                sa[reg] += e[nt][reg] * inv;
            }
        }
        barrier_nd();                        // publish bm

        // ---- GEMM2: acc[k][d] += b[k][t] * x[d][t]  (contract t=64)
        #pragma unroll
        for (int kt = 0; kt < 2; ++kt) {
            short8 af[4], bf[2];
            #pragma unroll
            for (int mt = 0; mt < 4; ++mt) {
                const int k = 16 * mt + m;
                af[mt] = *(const short8*)(
                    &bmm[k * TC + ((32 * kt + 8 * g) ^ (8 * (k & 7)))]);
            }
            #pragma unroll
            for (int nt2 = 0; nt2 < 2; ++nt2) {
                const int d = 32 * wv + 16 * nt2 + m;
                bf[nt2] = *(const short8*)(
                    &xs2[d * TC + ((32 * kt + 8 * g) ^ (8 * (d & 7)))]);
            }
            #pragma unroll
            for (int mt = 0; mt < 4; ++mt)
                #pragma unroll
                for (int nt2 = 0; nt2 < 2; ++nt2)
                    acc[mt][nt2] = __builtin_amdgcn_mfma_f32_16x16x32_bf16(
                        af[mt], bf[nt2], acc[mt][nt2], 0, 0, 0);
        }
    }

    // ---- epilogue: reassemble block partial in LDS, flush with 256B bursts
    barrier_nd();                            // xs dead -> reuse as fb [k][d]
    #pragma unroll
    for (int mt = 0; mt < 4; ++mt)
        #pragma unroll
        for (int nt2 = 0; nt2 < 2; ++nt2)
            #pragma unroll
            for (int reg = 0; reg < 4; ++reg)
                fb[(16 * mt + 4 * g + reg) * D + 32 * wv + 16 * nt2 + m] =
                    acc[mt][nt2][reg];
    barrier_nd();
    {
        float* vs = vout + (size_t)n * K * D;
        #pragma unroll
        for (int j = 0; j < 32; ++j) {
            const int off = wv * 2048 + j * 64 + ln;  // 64 lanes x 4B = 256B
            atomicAdd(&vs[off], fb[off]);
        }
    }
    #pragma unroll
    for (int reg = 0; reg < 4; ++reg) {
        float v = sa[reg];
        v += __shfl_xor(v, 1); v += __shfl_xor(v, 2);
        v += __shfl_xor(v, 4); v += __shfl_xor(v, 8);
        if (m == 0) atomicAdd(&suma[n * K + 16 * a + 4 * g + reg], v);
    }
}

// per (n,k): subtract suma*centroid, intra-normalize over d, accum final sumsq
__global__ void nv_finish_row(const float* __restrict__ cent,
                              const float* __restrict__ suma,
                              float* __restrict__ out,
                              float* __restrict__ nsum)
{
    const int bid = blockIdx.x;          // n*64 + k
    const int nn = bid >> 6, k = bid & 63;
    const int d = threadIdx.x;
    float v = out[(size_t)bid * D + d] - suma[bid] * cent[k * D + d];
    float sv = v * v;
    #pragma unroll
    for (int msk = 1; msk < 64; msk <<= 1) sv += __shfl_xor(sv, msk);
    __shared__ float red[4];
    __shared__ float stot;
    if ((d & 63) == 0) red[d >> 6] = sv;
    __syncthreads();
    if (d == 0) stot = red[0] + red[1] + red[2] + red[3];
    __syncthreads();
    const float s = stot;
    const float inv = 1.f / fmaxf(sqrtf(s), FEPS);
    out[(size_t)bid * D + d] = v * inv;
    if (d == 0) atomicAdd(&nsum[nn], s * inv * inv);
}

// final L2 over the flattened (K*D) per n
__global__ void nv_final(float* __restrict__ out, const float* __restrict__ nsum) {
    const int idx = blockIdx.x * 256 + threadIdx.x;
    const int n = idx >> 14;             // /16384
    out[idx] *= 1.f / fmaxf(sqrtf(nsum[n]), FEPS);
}

extern "C" void kernel_launch(void* const* d_in, const int* in_sizes, int n_in,
                              void* d_out, int out_size, void* d_ws, size_t ws_size,
                              hipStream_t stream)
{
    const float* x    = (const float*)d_in[0];
    const float* w    = (const float*)d_in[1];
    const float* cent = (const float*)d_in[2];
    float* out = (float*)d_out;

    // ws layout: suma[NB*K] | nsum[NB]
    float* suma = (float*)d_ws;
    float* nsum = suma + NB * K;

    hipMemsetAsync(d_ws, 0, (size_t)(NB * K + NB) * sizeof(float), stream);
    hipMemsetAsync(d_out, 0, (size_t)NB * K * D * sizeof(float), stream);

    nv_main<<<S * NB, 512, 0, stream>>>(x, w, out, suma);
    nv_finish_row<<<NB * K, 256, 0, stream>>>(cent, suma, out, nsum);
    nv_final<<<(NB * K * D) / 256, 256, 0, stream>>>(out, nsum);
}